// Round 7
// baseline (373.759 us; speedup 1.0000x reference)
//
#include <hip/hip_runtime.h>
#include <hip/hip_fp16.h>
#include <math.h>

#define L_  4096
#define B_  4
#define E_  1024
#define ND  16
#define BE  (B_*E_)       // 4096
#define COLS (BE*ND)      // 65536

// workspace layout (floats); F/G region sized by chunk count at launch
#define OFF_Q   0
#define OFF_W   (2*E_*ND)            // 32768
#define OFF_QC  (2*2*E_*ND)          // 65536
#define OFF_FS  (3*2*E_*ND)          // 98304

__device__ __forceinline__ float sigm(float x){ return 1.0f/(1.0f+__expf(-x)); }

// K0: q = 1-sigm(a)*sigm(d), w = sigm(a)*beta*gamma*scale, qc = q^CK (CK=1<<lg)
__global__ void k_params(const float* __restrict__ al,
                         const float* __restrict__ de,
                         const float* __restrict__ be,
                         const float* __restrict__ ga,
                         float* __restrict__ ws, int lg){
    int i = blockIdx.x*256 + threadIdx.x;          // [0, 2E*ND)
    float a = sigm(al[i]);
    float d = sigm(de[i]);
    float q = 1.0f - a*d;
    float w = a*be[i]*ga[i]*0.25f;                 // scale = sqrt(1/16) = 0.25
    float qc = q;
    for(int k=0;k<lg;k++) qc *= qc;                // q^CK
    ws[OFF_Q+i]=q; ws[OFF_W+i]=w; ws[OFF_QC+i]=qc;
}

// K1: per-chunk summaries. LDS-staged tile: coalesced float4 global loads,
// column-wise scan from LDS (conflict-free, 2-way alias). Single x read.
// F[c] = sum_j q^(CK-1-j) x_j (fwd recurrence), G[c] = sum_j q^j x_j (bwd recurrence).
template<int CK>
__global__ __launch_bounds__(128) void k_summ_t(const float* __restrict__ x,
                                                float* __restrict__ ws){
    constexpr int NC = L_/CK;
    __shared__ float tile[CK][128];
    const int tid = threadIdx.x;
    const int bid = blockIdx.x;
    const int c  = bid >> 5;
    const int b  = (bid >> 3) & 3;
    const int eg = bid & 7;
    const int e  = eg*128 + tid;
    const int t32 = tid & 31, r0 = tid >> 5;
    {   // stage: 4 rows per iter, 32 lanes x float4 = 512B contiguous per row
        const float* gp = x + (size_t)(c*CK + r0)*BE + b*E_ + eg*128 + 4*t32;
        #pragma unroll
        for(int it=0; it<CK/4; ++it)
            *(float4*)&tile[it*4 + r0][4*t32] = *(const float4*)(gp + (size_t)it*4*BE);
    }
    __syncthreads();
    const float* Q = ws + OFF_Q;
    const int col = (b*E_+e)*ND;
    {   // forward: F = q*F + x
        float qf[ND], F[ND];
        #pragma unroll
        for(int n=0;n<ND;n++){ qf[n]=Q[e*ND+n]; F[n]=0.f; }
        #pragma unroll
        for(int i=0;i<CK;i++){
            float xv = tile[i][tid];
            #pragma unroll
            for(int n=0;n<ND;n++) F[n]=fmaf(qf[n],F[n],xv);
        }
        float* Fp = ws + OFF_FS + (size_t)c*COLS + col;
        #pragma unroll
        for(int n=0;n<ND;n++) Fp[n]=F[n];
    }
    {   // backward: G = q*G + x (descending i) -> coeff of x_r is q^r
        float qb[ND], G[ND];
        #pragma unroll
        for(int n=0;n<ND;n++){ qb[n]=Q[(E_+e)*ND+n]; G[n]=0.f; }
        #pragma unroll
        for(int i=CK-1;i>=0;i--){
            float xv = tile[i][tid];
            #pragma unroll
            for(int n=0;n<ND;n++) G[n]=fmaf(qb[n],G[n],xv);
        }
        float* Gp = ws + OFF_FS + (size_t)NC*COLS + (size_t)c*COLS + col;
        #pragma unroll
        for(int n=0;n<ND;n++) Gp[n]=G[n];
    }
}

// K2: LDS-staged local scans + Horner truncated carries (CW chunks = 128-step
// window), fp32 acc in registers (full unroll, constant indices), fused
// residual + silu written back through the tile -> coalesced float4 stores.
template<int CK, int CW>
__global__ __launch_bounds__(128) void k_out2_t(const float* __restrict__ x,
                                                const float* __restrict__ om,
                                                const float* __restrict__ ws,
                                                float* __restrict__ out){
    constexpr int NC = L_/CK;
    __shared__ float tile[CK][128];
    const int tid = threadIdx.x;
    const int bid = blockIdx.x;
    const int c  = bid >> 5;
    const int b  = (bid >> 3) & 3;
    const int eg = bid & 7;
    const int e  = eg*128 + tid;
    const int t32 = tid & 31, r0 = tid >> 5;
    const size_t goff = (size_t)(c*CK + r0)*BE + b*E_ + eg*128 + 4*t32;
    {   // stage x
        const float* gp = x + goff;
        #pragma unroll
        for(int it=0; it<CK/4; ++it)
            *(float4*)&tile[it*4 + r0][4*t32] = *(const float4*)(gp + (size_t)it*4*BE);
    }
    __syncthreads();
    const float* Q  = ws + OFF_Q;
    const float* W  = ws + OFF_W;
    const float* FS = ws + OFF_FS;
    const float* GR = FS + (size_t)NC*COLS;
    const int col = (b*E_+e)*ND;
    const float omg = om[e];
    float acc[CK];

    // ---- forward: Horner carry S = sum_{j=1..CW} qc^{j-1} F[c-j], local scan ----
    {
        float st[ND];
        {
            float qc[ND];
            #pragma unroll
            for(int n=0;n<ND;n++){ qc[n]=ws[OFF_QC+e*ND+n]; st[n]=0.f; }
            int jm = (c < CW) ? c : CW;
            for(int j=jm; j>=1; --j){
                const float4* Fp = (const float4*)(FS + (size_t)(c-j)*COLS + col);
                #pragma unroll
                for(int v=0;v<4;v++){
                    float4 f = Fp[v];
                    st[4*v+0]=fmaf(qc[4*v+0],st[4*v+0],f.x);
                    st[4*v+1]=fmaf(qc[4*v+1],st[4*v+1],f.y);
                    st[4*v+2]=fmaf(qc[4*v+2],st[4*v+2],f.z);
                    st[4*v+3]=fmaf(qc[4*v+3],st[4*v+3],f.w);
                }
            }
        }
        float q1[ND], w1[ND];
        #pragma unroll
        for(int n=0;n<ND;n++){ q1[n]=Q[e*ND+n]; w1[n]=W[e*ND+n]; }
        #pragma unroll
        for(int i=0;i<CK;i++){
            float xv = tile[i][tid];
            #pragma unroll
            for(int n=0;n<ND;n++) st[n]=fmaf(q1[n],st[n],xv);
            float a0=xv*omg, a1=0.f;
            #pragma unroll
            for(int n=0;n<8;n++){ a0=fmaf(w1[n],st[n],a0); a1=fmaf(w1[n+8],st[n+8],a1); }
            acc[i]=a0+a1;
        }
    }

    // ---- backward: Horner carry R = sum_{j=1..CW} qc^{j-1} G[c+j], local scan,
    //      silu written into the tile (x[i] consumed before overwrite) ----
    {
        float rt[ND];
        {
            float qc[ND];
            #pragma unroll
            for(int n=0;n<ND;n++){ qc[n]=ws[OFF_QC+(E_+e)*ND+n]; rt[n]=0.f; }
            int jm = NC-1-c; if(jm>CW) jm=CW;
            for(int j=jm; j>=1; --j){
                const float4* Gp = (const float4*)(GR + (size_t)(c+j)*COLS + col);
                #pragma unroll
                for(int v=0;v<4;v++){
                    float4 g = Gp[v];
                    rt[4*v+0]=fmaf(qc[4*v+0],rt[4*v+0],g.x);
                    rt[4*v+1]=fmaf(qc[4*v+1],rt[4*v+1],g.y);
                    rt[4*v+2]=fmaf(qc[4*v+2],rt[4*v+2],g.z);
                    rt[4*v+3]=fmaf(qc[4*v+3],rt[4*v+3],g.w);
                }
            }
        }
        float q2[ND], w2[ND];
        #pragma unroll
        for(int n=0;n<ND;n++){ q2[n]=Q[(E_+e)*ND+n]; w2[n]=W[(E_+e)*ND+n]; }
        #pragma unroll
        for(int i=CK-1;i>=0;i--){
            float xv = tile[i][tid];
            float a0=acc[i], a1=0.f;
            #pragma unroll
            for(int n=0;n<8;n++){ a0=fmaf(w2[n],rt[n],a0); a1=fmaf(w2[n+8],rt[n+8],a1); }
            float z=a0+a1;
            tile[i][tid] = z / (1.0f + __expf(-z));
            #pragma unroll
            for(int n=0;n<ND;n++) rt[n]=fmaf(q2[n],rt[n],xv);
        }
    }
    __syncthreads();
    {   // cooperative coalesced store
        float* op = out + goff;
        #pragma unroll
        for(int it=0; it<CK/4; ++it)
            *(float4*)(op + (size_t)it*4*BE) = *(const float4*)&tile[it*4 + r0][4*t32];
    }
}

extern "C" void kernel_launch(void* const* d_in, const int* in_sizes, int n_in,
                              void* d_out, int out_size, void* d_ws, size_t ws_size,
                              hipStream_t stream) {
    const float* x  = (const float*)d_in[0];
    const float* al = (const float*)d_in[1];
    const float* de = (const float*)d_in[2];
    const float* be = (const float*)d_in[3];
    const float* ga = (const float*)d_in[4];
    const float* om = (const float*)d_in[5];
    float* ws = (float*)d_ws;
    float* out = (float*)d_out;

    // CK=32 needs 98304 + 2*128*65536 floats = 67.5 MB workspace (R3 confirmed ok)
    size_t need32 = ((size_t)OFF_FS + 2ull*(L_/32)*COLS) * sizeof(float);
    if (ws_size >= need32) {
        k_params<<<dim3((2*E_*ND)/256), dim3(256), 0, stream>>>(al, de, be, ga, ws, 5);
        k_summ_t<32>   <<<dim3((L_/32)*32), dim3(128), 0, stream>>>(x, ws);
        k_out2_t<32,4> <<<dim3((L_/32)*32), dim3(128), 0, stream>>>(x, om, ws, out);
    } else {
        k_params<<<dim3((2*E_*ND)/256), dim3(256), 0, stream>>>(al, de, be, ga, ws, 6);
        k_summ_t<64>   <<<dim3((L_/64)*32), dim3(128), 0, stream>>>(x, ws);
        k_out2_t<64,2> <<<dim3((L_/64)*32), dim3(128), 0, stream>>>(x, om, ws, out);
    }
}

// Round 8
// 186.208 us; speedup vs baseline: 2.0072x; 2.0072x over previous
//
#include <hip/hip_runtime.h>
#include <hip/hip_fp16.h>
#include <math.h>

#define L_  4096
#define B_  4
#define E_  1024
#define ND  16
#define BE  (B_*E_)       // 4096
#define COLS (BE*ND)      // 65536

// workspace layout (floats); F/G region sized by chunk count at launch
#define OFF_Q   0
#define OFF_W   (2*E_*ND)            // 32768
#define OFF_QC  (2*2*E_*ND)          // 65536
#define OFF_FS  (3*2*E_*ND)          // 98304

__device__ __forceinline__ float sigm(float x){ return 1.0f/(1.0f+__expf(-x)); }

// K0: q = 1-sigm(a)*sigm(d), w = sigm(a)*beta*gamma*scale, qc = q^CK (CK=1<<lg)
__global__ void k_params(const float* __restrict__ al,
                         const float* __restrict__ de,
                         const float* __restrict__ be,
                         const float* __restrict__ ga,
                         float* __restrict__ ws, int lg){
    int i = blockIdx.x*256 + threadIdx.x;          // [0, 2E*ND)
    float a = sigm(al[i]);
    float d = sigm(de[i]);
    float q = 1.0f - a*d;
    float w = a*be[i]*ga[i]*0.25f;                 // scale = sqrt(1/16) = 0.25
    float qc = q;
    for(int k=0;k<lg;k++) qc *= qc;                // q^CK
    ws[OFF_Q+i]=q; ws[OFF_W+i]=w; ws[OFF_QC+i]=qc;
}

// K1: per-chunk summaries. LDS-staged tile: coalesced float4 global loads,
// column reads from LDS (2-way alias = free). Single x read.
template<int CK, int THR>
__global__ __launch_bounds__(THR) void k_summ_t(const float* __restrict__ x,
                                                float* __restrict__ ws){
    constexpr int NC = L_/CK;
    constexpr int EG = E_/THR;
    constexpr int TPR = THR/4;            // threads per row (float4 each)
    __shared__ float tile[CK][THR];
    const int tid = threadIdx.x;
    const int bid = blockIdx.x;
    const int c  = bid / (B_*EG);
    const int b  = (bid / EG) % B_;
    const int eg = bid % EG;
    const int e  = eg*THR + tid;
    const int rr = tid / TPR, t4 = tid % TPR;
    {   // stage: 4 rows per iter, each row = TPR lanes x float4 contiguous
        const float* gp = x + (size_t)(c*CK + rr)*BE + b*E_ + eg*THR + 4*t4;
        #pragma unroll
        for(int it=0; it<CK/4; ++it)
            *(float4*)&tile[it*4 + rr][4*t4] = *(const float4*)(gp + (size_t)it*4*BE);
    }
    __syncthreads();
    const float* Q = ws + OFF_Q;
    const int col = (b*E_+e)*ND;
    {   // forward: F = q*F + x
        float qf[ND], F[ND];
        #pragma unroll
        for(int n=0;n<ND;n++){ qf[n]=Q[e*ND+n]; F[n]=0.f; }
        #pragma unroll
        for(int i=0;i<CK;i++){
            float xv = tile[i][tid];
            #pragma unroll
            for(int n=0;n<ND;n++) F[n]=fmaf(qf[n],F[n],xv);
        }
        float* Fp = ws + OFF_FS + (size_t)c*COLS + col;
        #pragma unroll
        for(int n=0;n<ND;n++) Fp[n]=F[n];
    }
    {   // backward: G = q*G + x (descending i) -> coeff of x_r is q^r
        float qb[ND], G[ND];
        #pragma unroll
        for(int n=0;n<ND;n++){ qb[n]=Q[(E_+e)*ND+n]; G[n]=0.f; }
        #pragma unroll
        for(int i=CK-1;i>=0;i--){
            float xv = tile[i][tid];
            #pragma unroll
            for(int n=0;n<ND;n++) G[n]=fmaf(qb[n],G[n],xv);
        }
        float* Gp = ws + OFF_FS + (size_t)NC*COLS + (size_t)c*COLS + col;
        #pragma unroll
        for(int n=0;n<ND;n++) Gp[n]=G[n];
    }
}

// K2: LDS-staged local scans + Horner truncated carries. Forward partials go
// to an fp16 LDS buffer (NOT a register array — R7: acc[CK] in regs -> VGPR
// 256 + 150 MB scratch spills). silu written back through the x tile so
// final stores are coalesced float4.
template<int CK, int CW, int THR>
__global__ __launch_bounds__(THR) void k_out2_t(const float* __restrict__ x,
                                                const float* __restrict__ om,
                                                const float* __restrict__ ws,
                                                float* __restrict__ out){
    constexpr int NC = L_/CK;
    constexpr int EG = E_/THR;
    constexpr int TPR = THR/4;
    __shared__ float tile[CK][THR];       // 32 KB at CK=32,THR=256
    __shared__ __half part[CK*THR];       // 16 KB
    const int tid = threadIdx.x;
    const int bid = blockIdx.x;
    const int c  = bid / (B_*EG);
    const int b  = (bid / EG) % B_;
    const int eg = bid % EG;
    const int e  = eg*THR + tid;
    const int rr = tid / TPR, t4 = tid % TPR;
    const size_t goff = (size_t)(c*CK + rr)*BE + b*E_ + eg*THR + 4*t4;
    {   // stage x (coalesced)
        const float* gp = x + goff;
        #pragma unroll
        for(int it=0; it<CK/4; ++it)
            *(float4*)&tile[it*4 + rr][4*t4] = *(const float4*)(gp + (size_t)it*4*BE);
    }
    __syncthreads();
    const float* Q  = ws + OFF_Q;
    const float* W  = ws + OFF_W;
    const float* FS = ws + OFF_FS;
    const float* GR = FS + (size_t)NC*COLS;
    const int col = (b*E_+e)*ND;
    const float omg = om[e];

    // ---- forward: Horner carry S = sum_{j=1..CW} qc^{j-1} F[c-j], local scan ----
    {
        float st[ND];
        {
            float qc[ND];
            #pragma unroll
            for(int n=0;n<ND;n++){ qc[n]=ws[OFF_QC+e*ND+n]; st[n]=0.f; }
            int jm = (c < CW) ? c : CW;
            for(int j=jm; j>=1; --j){
                const float4* Fp = (const float4*)(FS + (size_t)(c-j)*COLS + col);
                #pragma unroll
                for(int v=0;v<4;v++){
                    float4 f = Fp[v];
                    st[4*v+0]=fmaf(qc[4*v+0],st[4*v+0],f.x);
                    st[4*v+1]=fmaf(qc[4*v+1],st[4*v+1],f.y);
                    st[4*v+2]=fmaf(qc[4*v+2],st[4*v+2],f.z);
                    st[4*v+3]=fmaf(qc[4*v+3],st[4*v+3],f.w);
                }
            }
        }
        float q1[ND], w1[ND];
        #pragma unroll
        for(int n=0;n<ND;n++){ q1[n]=Q[e*ND+n]; w1[n]=W[e*ND+n]; }
        #pragma unroll
        for(int i=0;i<CK;i++){
            float xv = tile[i][tid];
            #pragma unroll
            for(int n=0;n<ND;n++) st[n]=fmaf(q1[n],st[n],xv);
            float a0=xv*omg, a1=0.f;
            #pragma unroll
            for(int n=0;n<8;n++){ a0=fmaf(w1[n],st[n],a0); a1=fmaf(w1[n+8],st[n+8],a1); }
            part[i*THR+tid] = __float2half_rn(a0+a1);
        }
    }

    // ---- backward: Horner carry R = sum_{j=1..CW} qc^{j-1} G[c+j], local scan;
    //      silu overwrites the tile (x consumed first), same-thread addresses ----
    {
        float rt[ND];
        {
            float qc[ND];
            #pragma unroll
            for(int n=0;n<ND;n++){ qc[n]=ws[OFF_QC+(E_+e)*ND+n]; rt[n]=0.f; }
            int jm = NC-1-c; if(jm>CW) jm=CW;
            for(int j=jm; j>=1; --j){
                const float4* Gp = (const float4*)(GR + (size_t)(c+j)*COLS + col);
                #pragma unroll
                for(int v=0;v<4;v++){
                    float4 g = Gp[v];
                    rt[4*v+0]=fmaf(qc[4*v+0],rt[4*v+0],g.x);
                    rt[4*v+1]=fmaf(qc[4*v+1],rt[4*v+1],g.y);
                    rt[4*v+2]=fmaf(qc[4*v+2],rt[4*v+2],g.z);
                    rt[4*v+3]=fmaf(qc[4*v+3],rt[4*v+3],g.w);
                }
            }
        }
        float q2[ND], w2[ND];
        #pragma unroll
        for(int n=0;n<ND;n++){ q2[n]=Q[(E_+e)*ND+n]; w2[n]=W[(E_+e)*ND+n]; }
        #pragma unroll
        for(int i=CK-1;i>=0;i--){
            float xv = tile[i][tid];
            float a0=0.f, a1=0.f;
            #pragma unroll
            for(int n=0;n<8;n++){ a0=fmaf(w2[n],rt[n],a0); a1=fmaf(w2[n+8],rt[n+8],a1); }
            float z = __half2float(part[i*THR+tid]) + a0 + a1;
            tile[i][tid] = z / (1.0f + __expf(-z));
            #pragma unroll
            for(int n=0;n<ND;n++) rt[n]=fmaf(q2[n],rt[n],xv);
        }
    }
    __syncthreads();
    {   // cooperative coalesced store
        float* op = out + goff;
        #pragma unroll
        for(int it=0; it<CK/4; ++it)
            *(float4*)(op + (size_t)it*4*BE) = *(const float4*)&tile[it*4 + rr][4*t4];
    }
}

extern "C" void kernel_launch(void* const* d_in, const int* in_sizes, int n_in,
                              void* d_out, int out_size, void* d_ws, size_t ws_size,
                              hipStream_t stream) {
    const float* x  = (const float*)d_in[0];
    const float* al = (const float*)d_in[1];
    const float* de = (const float*)d_in[2];
    const float* be = (const float*)d_in[3];
    const float* ga = (const float*)d_in[4];
    const float* om = (const float*)d_in[5];
    float* ws = (float*)d_ws;
    float* out = (float*)d_out;

    // CK=32 needs 98304 + 2*128*65536 floats = 67.5 MB workspace (R3/R7 ok)
    size_t need32 = ((size_t)OFF_FS + 2ull*(L_/32)*COLS) * sizeof(float);
    if (ws_size >= need32) {
        k_params<<<dim3((2*E_*ND)/256), dim3(256), 0, stream>>>(al, de, be, ga, ws, 5);
        k_summ_t<32,256>   <<<dim3((L_/32)*B_*(E_/256)), dim3(256), 0, stream>>>(x, ws);
        k_out2_t<32,4,256> <<<dim3((L_/32)*B_*(E_/256)), dim3(256), 0, stream>>>(x, om, ws, out);
    } else {
        k_params<<<dim3((2*E_*ND)/256), dim3(256), 0, stream>>>(al, de, be, ga, ws, 6);
        k_summ_t<64,128>   <<<dim3((L_/64)*B_*(E_/128)), dim3(128), 0, stream>>>(x, ws);
        k_out2_t<64,2,128> <<<dim3((L_/64)*B_*(E_/128)), dim3(128), 0, stream>>>(x, om, ws, out);
    }
}